// Round 11
// baseline (6332.318 us; speedup 1.0000x reference)
//
#include <hip/hip_runtime.h>
#include <hip/hip_bf16.h>
#include <math.h>

// BS=1, L=2048, D=4096. DECODED (r10): d_out is FP32[2048] — the "(bf16,...)"
// in the harness error label is a hardcoded f-string, not the out dtype; ref
// is bf16-rounded for thresholding only. All rounds wrote bf16 -> first half
// junk, second half zeros -> absmax == ref[1024:].max() == 9.918e-4 const
// (r7's lone deviation = junk@argmax dipping low). Inputs fp32, documented
// order. ROUND 11: r3 pipeline (printed jax semantics, fp32 math), FP32 out.

#define LDSW 132  // 128 + 4 pad

// Generic 128x128 tile GEMM, 16x16 threads, 8x8 microtile, BK=16, fp32.
// MODE_A: 0 -> A[i*lda+k], 1 -> A[k*lda+i]
// MODE_B: 0 -> B[k*ldb+j], 1 -> B[j*ldb+k]
// EPI: 0 -> C[i*ldc+j] = acc ; 1 -> colsum[j] += sum_i tanh(acc)
template<int MODE_A, int MODE_B, int EPI>
__global__ __launch_bounds__(256) void gemm_tile(
    const float* __restrict__ A, const float* __restrict__ B,
    float* __restrict__ C, float* __restrict__ colsum, size_t aoff,
    int K, int lda, int ldb, int ldc)
{
  __shared__ float As[16][LDSW];
  __shared__ float Bs[16][LDSW];
  const int tx = threadIdx.x, ty = threadIdx.y;
  const int t  = ty * 16 + tx;
  const int i0 = blockIdx.y * 128;
  const int j0 = blockIdx.x * 128;

  float acc[8][8];
  #pragma unroll
  for (int r = 0; r < 8; r++)
    #pragma unroll
    for (int c = 0; c < 8; c++) acc[r][c] = 0.f;

  for (int k0 = 0; k0 < K; k0 += 16) {
    if (MODE_A == 1) {              // A[k*lda+i]: contiguous along i
      #pragma unroll
      for (int u = 0; u < 2; u++) {
        int vid = t + u * 256;
        int kl = vid >> 5, i4 = (vid & 31) * 4;
        float4 v = *(const float4*)&A[(size_t)(k0 + kl) * lda + i0 + i4 + aoff];
        *(float4*)&As[kl][i4] = v;
      }
    } else {                        // A[i*lda+k]: transpose into LDS
      #pragma unroll
      for (int u = 0; u < 2; u++) {
        int vid = t + u * 256;
        int il = vid >> 2, kq = (vid & 3) * 4;
        float4 v = *(const float4*)&A[(size_t)(i0 + il) * lda + k0 + kq + aoff];
        As[kq + 0][il] = v.x; As[kq + 1][il] = v.y;
        As[kq + 2][il] = v.z; As[kq + 3][il] = v.w;
      }
    }
    if (MODE_B == 0) {              // B[k*ldb+j]
      #pragma unroll
      for (int u = 0; u < 2; u++) {
        int vid = t + u * 256;
        int kl = vid >> 5, j4 = (vid & 31) * 4;
        float4 v = *(const float4*)&B[(size_t)(k0 + kl) * ldb + j0 + j4];
        *(float4*)&Bs[kl][j4] = v;
      }
    } else {                        // B[j*ldb+k]
      #pragma unroll
      for (int u = 0; u < 2; u++) {
        int vid = t + u * 256;
        int jl = vid >> 2, kq = (vid & 3) * 4;
        float4 v = *(const float4*)&B[(size_t)(j0 + jl) * ldb + k0 + kq];
        Bs[kq + 0][jl] = v.x; Bs[kq + 1][jl] = v.y;
        Bs[kq + 2][jl] = v.z; Bs[kq + 3][jl] = v.w;
      }
    }
    __syncthreads();

    #pragma unroll
    for (int k = 0; k < 16; k++) {
      float4 a0 = *(float4*)&As[k][ty * 4];
      float4 a1 = *(float4*)&As[k][64 + ty * 4];
      float4 b0 = *(float4*)&Bs[k][tx * 4];
      float4 b1 = *(float4*)&Bs[k][64 + tx * 4];
      float a[8] = {a0.x, a0.y, a0.z, a0.w, a1.x, a1.y, a1.z, a1.w};
      float b[8] = {b0.x, b0.y, b0.z, b0.w, b1.x, b1.y, b1.z, b1.w};
      #pragma unroll
      for (int r = 0; r < 8; r++)
        #pragma unroll
        for (int c = 0; c < 8; c++)
          acc[r][c] += a[r] * b[c];
    }
    __syncthreads();
  }

  if (EPI == 0) {
    #pragma unroll
    for (int r = 0; r < 8; r++) {
      int i = i0 + (r < 4 ? ty * 4 + r : 64 + ty * 4 + (r - 4));
      float4 v0 = make_float4(acc[r][0], acc[r][1], acc[r][2], acc[r][3]);
      float4 v1 = make_float4(acc[r][4], acc[r][5], acc[r][6], acc[r][7]);
      *(float4*)&C[(size_t)i * ldc + j0 + tx * 4] = v0;
      *(float4*)&C[(size_t)i * ldc + j0 + 64 + tx * 4] = v1;
    }
  } else {
    float cs[8];
    #pragma unroll
    for (int c = 0; c < 8; c++) {
      float s = 0.f;
      #pragma unroll
      for (int r = 0; r < 8; r++) s += tanhf(acc[r][c]);
      cs[c] = s;
    }
    __syncthreads();
    #pragma unroll
    for (int c = 0; c < 4; c++) {
      As[ty][tx * 4 + c]      = cs[c];
      As[ty][64 + tx * 4 + c] = cs[4 + c];
    }
    __syncthreads();
    if (t < 128) {
      float s = 0.f;
      #pragma unroll
      for (int r = 0; r < 16; r++) s += As[r][t];
      atomicAdd(&colsum[j0 + t], s);
    }
  }
}

// Row softmax over 4096-wide rows, one block per row, in place.
__global__ __launch_bounds__(256) void softmax_rows(float* __restrict__ S)
{
  const int row = blockIdx.x;
  float* p = S + (size_t)row * 4096;
  const int tid = threadIdx.x;
  float4 v[4];
  #pragma unroll
  for (int u = 0; u < 4; u++) v[u] = ((const float4*)p)[tid + u * 256];

  float m = -3.4e38f;
  #pragma unroll
  for (int u = 0; u < 4; u++)
    m = fmaxf(m, fmaxf(fmaxf(v[u].x, v[u].y), fmaxf(v[u].z, v[u].w)));
  #pragma unroll
  for (int off = 32; off > 0; off >>= 1) m = fmaxf(m, __shfl_down(m, off, 64));
  __shared__ float redm[4];
  if ((tid & 63) == 0) redm[tid >> 6] = m;
  __syncthreads();
  m = fmaxf(fmaxf(redm[0], redm[1]), fmaxf(redm[2], redm[3]));

  float s = 0.f;
  #pragma unroll
  for (int u = 0; u < 4; u++) {
    v[u].x = __expf(v[u].x - m); v[u].y = __expf(v[u].y - m);
    v[u].z = __expf(v[u].z - m); v[u].w = __expf(v[u].w - m);
    s += v[u].x + v[u].y + v[u].z + v[u].w;
  }
  #pragma unroll
  for (int off = 32; off > 0; off >>= 1) s += __shfl_down(s, off, 64);
  __shared__ float reds[4];
  if ((tid & 63) == 0) reds[tid >> 6] = s;
  __syncthreads();
  s = reds[0] + reds[1] + reds[2] + reds[3];

  const float inv = 1.f / s;
  #pragma unroll
  for (int u = 0; u < 4; u++) {
    v[u].x *= inv; v[u].y *= inv; v[u].z *= inv; v[u].w *= inv;
    ((float4*)p)[tid + u * 256] = v[u];
  }
}

__global__ void zero_k(float* p, int n)
{
  int i = blockIdx.x * 256 + threadIdx.x;
  if (i < n) p[i] = 0.f;
}

// scores /= max(scores); softmax; -> FP32 out (2048 floats).
__global__ __launch_bounds__(256) void finalize_k(const float* __restrict__ scores,
                                                  float* __restrict__ out)
{
  const int tid = threadIdx.x;
  float s[8];
  #pragma unroll
  for (int u = 0; u < 8; u++) s[u] = scores[tid + u * 256];

  __shared__ float red[4];

  float m = -3.4e38f;
  #pragma unroll
  for (int u = 0; u < 8; u++) m = fmaxf(m, s[u]);
  #pragma unroll
  for (int off = 32; off > 0; off >>= 1) m = fmaxf(m, __shfl_down(m, off, 64));
  if ((tid & 63) == 0) red[tid >> 6] = m;
  __syncthreads();
  m = fmaxf(fmaxf(red[0], red[1]), fmaxf(red[2], red[3]));
  __syncthreads();

  const float inv1 = 1.f / m;
  #pragma unroll
  for (int u = 0; u < 8; u++) s[u] *= inv1;

  float m2 = -3.4e38f;
  #pragma unroll
  for (int u = 0; u < 8; u++) m2 = fmaxf(m2, s[u]);
  #pragma unroll
  for (int off = 32; off > 0; off >>= 1) m2 = fmaxf(m2, __shfl_down(m2, off, 64));
  if ((tid & 63) == 0) red[tid >> 6] = m2;
  __syncthreads();
  m2 = fmaxf(fmaxf(red[0], red[1]), fmaxf(red[2], red[3]));
  __syncthreads();

  float sum = 0.f;
  #pragma unroll
  for (int u = 0; u < 8; u++) { s[u] = expf(s[u] - m2); sum += s[u]; }
  #pragma unroll
  for (int off = 32; off > 0; off >>= 1) sum += __shfl_down(sum, off, 64);
  if ((tid & 63) == 0) red[tid >> 6] = sum;
  __syncthreads();
  sum = red[0] + red[1] + red[2] + red[3];

  const float invs = 1.f / sum;
  #pragma unroll
  for (int u = 0; u < 8; u++)
    out[tid + u * 256] = s[u] * invs;          // FP32 store
}

extern "C" void kernel_launch(void* const* d_in, const int* in_sizes, int n_in,
                              void* d_out, int out_size, void* d_ws, size_t ws_size,
                              hipStream_t stream)
{
  const float* T    = (const float*)d_in[0];   // [2048][4096]
  const float* Win  = (const float*)d_in[1];   // [2048][2048] 'ml'
  const float* Wout = (const float*)d_in[2];   // [2048][4096] 'lc'
  float* out = (float*)d_out;                  // FP32[2048]

  int R = 1024;
  if (ws_size < (size_t)2 * 1024 * 4096 * 4 + 8192 + 64) R = 512;
  if (ws_size < (size_t)2 * 512 * 4096 * 4 + 8192 + 64) R = 256;

  float* Comb   = (float*)d_ws;                // [R][4096]: mix | Q
  float* Sc     = Comb + (size_t)R * 4096;     // [R][4096]
  float* scores = Sc + (size_t)R * 4096;       // [2048]

  dim3 blk(16, 16);

  zero_k<<<8, 256, 0, stream>>>(scores, 2048);

  const int nchunk = 4096 / R;
  for (int c = 0; c < nchunk; c++) {
    const size_t d0 = (size_t)c * R;
    // GEMM1c: Q[d'][m] = sum_l T[l][d0+d'] * Win[m][l]  -> Comb[:, 2048:]
    gemm_tile<1, 1, 0><<<dim3(16, R / 128), blk, 0, stream>>>(
        T, Win, Comb + 2048, nullptr, d0, 2048, 4096, 2048, 4096);
    // GEMM2c: S[q][k] = sum_l Q[q][l] * T[l][k]
    gemm_tile<0, 0, 0><<<dim3(32, R / 128), blk, 0, stream>>>(
        Comb + 2048, T, Sc, nullptr, 0, 2048, 4096, 4096, 4096);
    softmax_rows<<<R, 256, 0, stream>>>(Sc);
    // GEMM3c: mix[q][l] = sum_k A[q][k] * T[l][k]  -> Comb[:, 0:2048]
    gemm_tile<0, 1, 0><<<dim3(16, R / 128), blk, 0, stream>>>(
        Sc, T, Comb, nullptr, 0, 4096, 4096, 4096, 4096);
    // GEMM4c: Z[d][l] = sum_c Comb[d][c] * Wout[l][c]; scores[l] += tanh(Z)
    gemm_tile<0, 1, 1><<<dim3(16, R / 128), blk, 0, stream>>>(
        Comb, Wout, nullptr, scores, 0, 4096, 4096, 4096, 4096);
  }

  finalize_k<<<1, 256, 0, stream>>>(scores, out);
}

// Round 12
// 997.650 us; speedup vs baseline: 6.3472x; 6.3472x over previous
//
#include <hip/hip_runtime.h>
#include <hip/hip_bf16.h>
#include <math.h>

// BS=1, L=2048, D=4096. PASSED r11 (fp32 vector, 6332us): inputs fp32 in
// documented order, out fp32[2048], printed-jax semantics exact.
// ROUND 12: bf16 MFMA GEMMs (16x16x32), all operands staged k-contiguous via
// one-time Tt_bf transpose. ws = 64.01MB <= 67.1MB (proven >= by r5).

typedef __attribute__((ext_vector_type(8))) short short8;
typedef __attribute__((ext_vector_type(4))) float f32x4;

#define PAD 40  // LDS row stride in bf16 (32 + 8): <=2-way bank aliasing

__device__ inline unsigned short f2bf(float f) {
  unsigned u = __float_as_uint(f);
  return (unsigned short)((u + 0x7FFF + ((u >> 16) & 1)) >> 16);  // RNE
}

// 128x128-tile bf16 MFMA GEMM. C[i][j] = sum_k A[i][k]*B[j][k] (both k-major).
// AF32/BF32: operand source dtype (1 = fp32, cvt inline during staging).
// CMODE: 0 -> C fp32 store; 1 -> C bf16 store; 2 -> colsum[j] += sum_i tanh.
template<int AF32, int BF32, int CMODE>
__global__ __launch_bounds__(256) void mfma_gemm(
    const void* __restrict__ Av, const void* __restrict__ Bv,
    void* __restrict__ Cv, float* __restrict__ colsum,
    int K, int lda, int ldb, int ldc)
{
  __shared__ unsigned short As[128 * PAD];
  __shared__ unsigned short Bs[128 * PAD];
  const int t = threadIdx.x;
  const int lane = t & 63;
  const int wid = t >> 6;
  const int wm = (wid >> 1) * 64, wn = (wid & 1) * 64;
  const int i0 = blockIdx.y * 128, j0 = blockIdx.x * 128;
  const int lr = lane & 15, lq = lane >> 4;

  f32x4 acc[4][4];
  #pragma unroll
  for (int a = 0; a < 4; a++)
    #pragma unroll
    for (int b = 0; b < 4; b++) acc[a][b] = (f32x4){0.f, 0.f, 0.f, 0.f};

  for (int k0 = 0; k0 < K; k0 += 32) {
    #pragma unroll
    for (int u = 0; u < 2; u++) {
      int vid = t + u * 256;
      int row = vid >> 2, kq = (vid & 3) * 8;
      if (AF32) {
        const float* s = (const float*)Av + (size_t)(i0 + row) * lda + k0 + kq;
        float4 f0 = *(const float4*)s;
        float4 f1 = *(const float4*)(s + 4);
        union { unsigned short h[8]; int4 v; } pk;
        pk.h[0] = f2bf(f0.x); pk.h[1] = f2bf(f0.y);
        pk.h[2] = f2bf(f0.z); pk.h[3] = f2bf(f0.w);
        pk.h[4] = f2bf(f1.x); pk.h[5] = f2bf(f1.y);
        pk.h[6] = f2bf(f1.z); pk.h[7] = f2bf(f1.w);
        *(int4*)&As[row * PAD + kq] = pk.v;
      } else {
        const unsigned short* s =
            (const unsigned short*)Av + (size_t)(i0 + row) * lda + k0 + kq;
        *(int4*)&As[row * PAD + kq] = *(const int4*)s;
      }
    }
    #pragma unroll
    for (int u = 0; u < 2; u++) {
      int vid = t + u * 256;
      int row = vid >> 2, kq = (vid & 3) * 8;
      if (BF32) {
        const float* s = (const float*)Bv + (size_t)(j0 + row) * ldb + k0 + kq;
        float4 f0 = *(const float4*)s;
        float4 f1 = *(const float4*)(s + 4);
        union { unsigned short h[8]; int4 v; } pk;
        pk.h[0] = f2bf(f0.x); pk.h[1] = f2bf(f0.y);
        pk.h[2] = f2bf(f0.z); pk.h[3] = f2bf(f0.w);
        pk.h[4] = f2bf(f1.x); pk.h[5] = f2bf(f1.y);
        pk.h[6] = f2bf(f1.z); pk.h[7] = f2bf(f1.w);
        *(int4*)&Bs[row * PAD + kq] = pk.v;
      } else {
        const unsigned short* s =
            (const unsigned short*)Bv + (size_t)(j0 + row) * ldb + k0 + kq;
        *(int4*)&Bs[row * PAD + kq] = *(const int4*)s;
      }
    }
    __syncthreads();

    short8 af[4], bfr[4];
    #pragma unroll
    for (int tm = 0; tm < 4; tm++)
      af[tm] = *(const short8*)&As[(wm + tm * 16 + lr) * PAD + lq * 8];
    #pragma unroll
    for (int tn = 0; tn < 4; tn++)
      bfr[tn] = *(const short8*)&Bs[(wn + tn * 16 + lr) * PAD + lq * 8];

    #pragma unroll
    for (int tm = 0; tm < 4; tm++)
      #pragma unroll
      for (int tn = 0; tn < 4; tn++)
        acc[tm][tn] = __builtin_amdgcn_mfma_f32_16x16x32_bf16(
            af[tm], bfr[tn], acc[tm][tn], 0, 0, 0);
    __syncthreads();
  }

  if (CMODE == 2) {
    // Z=acc -> tanh -> column sums. C/D: col=lane&15, row=lq*4+reg.
    #pragma unroll
    for (int tn = 0; tn < 4; tn++) {
      float s = 0.f;
      #pragma unroll
      for (int tm = 0; tm < 4; tm++)
        #pragma unroll
        for (int r = 0; r < 4; r++) s += tanhf(acc[tm][tn][r]);
      s += __shfl_xor(s, 16);
      s += __shfl_xor(s, 32);
      if (lq == 0) atomicAdd(&colsum[j0 + wn + tn * 16 + lr], s);
    }
  } else {
    #pragma unroll
    for (int tm = 0; tm < 4; tm++)
      #pragma unroll
      for (int tn = 0; tn < 4; tn++)
        #pragma unroll
        for (int r = 0; r < 4; r++) {
          int row = i0 + wm + tm * 16 + lq * 4 + r;
          int col = j0 + wn + tn * 16 + lr;
          if (CMODE == 0)
            ((float*)Cv)[(size_t)row * ldc + col] = acc[tm][tn][r];
          else
            ((unsigned short*)Cv)[(size_t)row * ldc + col] = f2bf(acc[tm][tn][r]);
        }
  }
}

// Tt_bf[key][l] = bf16(T[l][key]); T [2048][4096] fp32.
__global__ __launch_bounds__(256) void transpose_bf16(
    const float* __restrict__ T, unsigned short* __restrict__ Tt)
{
  __shared__ float tile[64][65];
  const int tx = threadIdx.x & 63;
  const int ty = threadIdx.x >> 6;   // 0..3
  const int k0 = blockIdx.x * 64;    // key axis (4096)
  const int l0 = blockIdx.y * 64;    // l axis (2048)
  #pragma unroll
  for (int u = 0; u < 16; u++) {
    int row = ty * 16 + u;
    tile[row][tx] = T[(size_t)(l0 + row) * 4096 + k0 + tx];
  }
  __syncthreads();
  #pragma unroll
  for (int u = 0; u < 16; u++) {
    int row = ty * 16 + u;
    Tt[(size_t)(k0 + row) * 2048 + l0 + tx] = f2bf(tile[tx][row]);
  }
}

// Row softmax over 4096 fp32, writes bf16 result IN PLACE (row start).
// Thread owns 16 contiguous values -> packed int4 bf16 stores.
__global__ __launch_bounds__(256) void softmax_bf16(float* __restrict__ S)
{
  float* p = S + (size_t)blockIdx.x * 4096;
  const int tid = threadIdx.x;
  float4 v[4];
  #pragma unroll
  for (int u = 0; u < 4; u++) v[u] = ((const float4*)p)[tid * 4 + u];

  float m = -3.4e38f;
  #pragma unroll
  for (int u = 0; u < 4; u++)
    m = fmaxf(m, fmaxf(fmaxf(v[u].x, v[u].y), fmaxf(v[u].z, v[u].w)));
  #pragma unroll
  for (int off = 32; off > 0; off >>= 1) m = fmaxf(m, __shfl_down(m, off, 64));
  __shared__ float redm[4];
  if ((tid & 63) == 0) redm[tid >> 6] = m;
  __syncthreads();
  m = fmaxf(fmaxf(redm[0], redm[1]), fmaxf(redm[2], redm[3]));

  float s = 0.f;
  #pragma unroll
  for (int u = 0; u < 4; u++) {
    v[u].x = __expf(v[u].x - m); v[u].y = __expf(v[u].y - m);
    v[u].z = __expf(v[u].z - m); v[u].w = __expf(v[u].w - m);
    s += v[u].x + v[u].y + v[u].z + v[u].w;
  }
  #pragma unroll
  for (int off = 32; off > 0; off >>= 1) s += __shfl_down(s, off, 64);
  __shared__ float reds[4];
  if ((tid & 63) == 0) reds[tid >> 6] = s;
  __syncthreads();
  s = reds[0] + reds[1] + reds[2] + reds[3];
  const float inv = 1.f / s;

  unsigned short* a = (unsigned short*)p;
  #pragma unroll
  for (int h = 0; h < 2; h++) {
    union { unsigned short u[8]; int4 q; } pk;
    #pragma unroll
    for (int j = 0; j < 2; j++) {
      float4 w = v[h * 2 + j];
      pk.u[j * 4 + 0] = f2bf(w.x * inv); pk.u[j * 4 + 1] = f2bf(w.y * inv);
      pk.u[j * 4 + 2] = f2bf(w.z * inv); pk.u[j * 4 + 3] = f2bf(w.w * inv);
    }
    ((int4*)a)[tid * 2 + h] = pk.q;
  }
}

__global__ void zero_k(float* p, int n)
{
  int i = blockIdx.x * 256 + threadIdx.x;
  if (i < n) p[i] = 0.f;
}

// scores /= max(scores); softmax; -> FP32 out (2048).
__global__ __launch_bounds__(256) void finalize_k(const float* __restrict__ scores,
                                                  float* __restrict__ out)
{
  const int tid = threadIdx.x;
  float s[8];
  #pragma unroll
  for (int u = 0; u < 8; u++) s[u] = scores[tid + u * 256];

  __shared__ float red[4];

  float m = -3.4e38f;
  #pragma unroll
  for (int u = 0; u < 8; u++) m = fmaxf(m, s[u]);
  #pragma unroll
  for (int off = 32; off > 0; off >>= 1) m = fmaxf(m, __shfl_down(m, off, 64));
  if ((tid & 63) == 0) red[tid >> 6] = m;
  __syncthreads();
  m = fmaxf(fmaxf(red[0], red[1]), fmaxf(red[2], red[3]));
  __syncthreads();

  const float inv1 = 1.f / m;
  #pragma unroll
  for (int u = 0; u < 8; u++) s[u] *= inv1;

  float m2 = -3.4e38f;
  #pragma unroll
  for (int u = 0; u < 8; u++) m2 = fmaxf(m2, s[u]);
  #pragma unroll
  for (int off = 32; off > 0; off >>= 1) m2 = fmaxf(m2, __shfl_down(m2, off, 64));
  if ((tid & 63) == 0) red[tid >> 6] = m2;
  __syncthreads();
  m2 = fmaxf(fmaxf(red[0], red[1]), fmaxf(red[2], red[3]));
  __syncthreads();

  float sum = 0.f;
  #pragma unroll
  for (int u = 0; u < 8; u++) { s[u] = expf(s[u] - m2); sum += s[u]; }
  #pragma unroll
  for (int off = 32; off > 0; off >>= 1) sum += __shfl_down(sum, off, 64);
  if ((tid & 63) == 0) red[tid >> 6] = sum;
  __syncthreads();
  sum = red[0] + red[1] + red[2] + red[3];

  const float invs = 1.f / sum;
  #pragma unroll
  for (int u = 0; u < 8; u++)
    out[tid + u * 256] = s[u] * invs;
}

extern "C" void kernel_launch(void* const* d_in, const int* in_sizes, int n_in,
                              void* d_out, int out_size, void* d_ws, size_t ws_size,
                              hipStream_t stream)
{
  const float* T    = (const float*)d_in[0];   // [2048][4096]
  const float* Win  = (const float*)d_in[1];   // [2048][2048] 'ml'
  const float* Wout = (const float*)d_in[2];   // [2048][4096] 'lc'
  float* out = (float*)d_out;                  // FP32[2048]

  // ws: Tt_bf [4096][2048] bf16 (16MB) | comb [4096][4096] bf16 (32MB:
  //     cols 0:2048 mix, 2048:4096 Q) | S [1024][4096] fp32 (16MB, softmax
  //     rewrites rows as bf16 in place) | scores [2048] fp32.  Total 64.01MB.
  unsigned short* Tt   = (unsigned short*)d_ws;
  unsigned short* comb = Tt + (size_t)4096 * 2048;
  float* S      = (float*)(comb + (size_t)4096 * 4096);
  float* scores = S + (size_t)1024 * 4096;

  zero_k<<<8, 256, 0, stream>>>(scores, 2048);
  transpose_bf16<<<dim3(64, 32), 256, 0, stream>>>(T, Tt);

  // GEMM1: Q[d][m] = sum_l ctx[d][l]*Win[m][l] -> comb[:,2048:] (bf16 out)
  mfma_gemm<0, 1, 1><<<dim3(16, 32), 256, 0, stream>>>(
      Tt, Win, comb + 2048, nullptr, 2048, 2048, 2048, 4096);

  for (int c = 0; c < 4; c++) {
    const size_t d0 = (size_t)c * 1024;
    // GEMM2: S[q][key] = sum_l Q[q][l]*ctx[key][l]  (fp32 out)
    mfma_gemm<0, 0, 0><<<dim3(32, 8), 256, 0, stream>>>(
        comb + d0 * 4096 + 2048, Tt, S, nullptr, 2048, 4096, 2048, 4096);
    softmax_bf16<<<1024, 256, 0, stream>>>(S);
    // GEMM3: mix[q][l] = sum_key A[q][key]*T[l][key] -> comb[:,0:2048]
    mfma_gemm<0, 1, 1><<<dim3(16, 8), 256, 0, stream>>>(
        (unsigned short*)S, T, comb + d0 * 4096, nullptr, 4096, 8192, 4096, 4096);
  }

  // GEMM4: Z[d][l] = sum_c comb[d][c]*Wout[l][c]; scores[l] += tanh-colsum
  mfma_gemm<0, 1, 2><<<dim3(16, 32), 256, 0, stream>>>(
      comb, Wout, nullptr, scores, 4096, 4096, 4096, 4096);

  finalize_k<<<1, 256, 0, stream>>>(scores, out);
}

// Round 13
// 503.188 us; speedup vs baseline: 12.5844x; 1.9827x over previous
//
#include <hip/hip_runtime.h>
#include <hip/hip_bf16.h>
#include <math.h>

// BS=1, L=2048, D=4096. r12 PASSED (998us, absmax 1.14e-5, thr 2.56e-5).
// r13: (1) global_load_lds width=16 DMA staging for all bf16 operands with
// no-pad [128][32] LDS layout (provably at LDS bank floor for writes+reads);
// (2) ws-adaptive tiers: if ws fits, pre-convert Win/Wout/T to bf16 once ->
// all-DMA staging + bigger S chunk (higher grid occupancy). Proven ws >=
// 67,117,056 B (tier0 exact fit). Math/rounding identical to r12.

typedef __attribute__((ext_vector_type(8))) short short8;
typedef __attribute__((ext_vector_type(4))) float f32x4;

__device__ __forceinline__ unsigned short f2bf(float f) {
  unsigned u = __float_as_uint(f);
  return (unsigned short)((u + 0x7FFF + ((u >> 16) & 1)) >> 16);  // RNE
}

typedef const __attribute__((address_space(1))) unsigned int* gas_t;
typedef __attribute__((address_space(3))) unsigned int* las_t;
__device__ __forceinline__ void dma16(const unsigned short* g, unsigned short* l)
{
  __builtin_amdgcn_global_load_lds((gas_t)(const void*)g, (las_t)(void*)l,
                                   16, 0, 0);
}

// 128x128-tile bf16 MFMA GEMM: C[i][j] = sum_k A[i][k]*B[j][k], k-major both.
// A is always bf16 (DMA). BF32: 1 -> B fp32, VALU cvt staging; 0 -> bf16 DMA.
// CMODE: 0 -> C fp32; 1 -> C bf16; 2 -> colsum[j] += sum_i tanh(acc).
// LDS: no-pad [row][k] bf16, lane dest = vid*16B (contiguous; bank-floor).
template<int BF32, int CMODE>
__global__ __launch_bounds__(256) void mfma_gemm(
    const unsigned short* __restrict__ Abf, const void* __restrict__ Bv,
    void* __restrict__ Cv, float* __restrict__ colsum,
    int K, int lda, int ldb, int ldc)
{
  __shared__ unsigned short As[128 * 32];
  __shared__ unsigned short Bs[128 * 32];
  const int t = threadIdx.x;
  const int lane = t & 63, wid = t >> 6;
  const int wm = (wid >> 1) * 64, wn = (wid & 1) * 64;
  const int i0 = blockIdx.y * 128, j0 = blockIdx.x * 128;
  const int lr = lane & 15, lq = lane >> 4;

  f32x4 acc[4][4];
  #pragma unroll
  for (int a = 0; a < 4; a++)
    #pragma unroll
    for (int b = 0; b < 4; b++) acc[a][b] = (f32x4){0.f, 0.f, 0.f, 0.f};

  for (int k0 = 0; k0 < K; k0 += 32) {
    // ---- A staging: bf16 DMA (dest = wave base + lane*16) ----
    #pragma unroll
    for (int u = 0; u < 2; u++) {
      int vid = u * 256 + t;
      int row = vid >> 2, kq = (vid & 3) * 8;
      dma16(Abf + (size_t)(i0 + row) * lda + k0 + kq,
            &As[(u * 256 + wid * 64) * 8]);
    }
    // ---- B staging ----
    if (BF32 == 0) {
      #pragma unroll
      for (int u = 0; u < 2; u++) {
        int vid = u * 256 + t;
        int row = vid >> 2, kq = (vid & 3) * 8;
        dma16((const unsigned short*)Bv + (size_t)(j0 + row) * ldb + k0 + kq,
              &Bs[(u * 256 + wid * 64) * 8]);
      }
    } else {
      #pragma unroll
      for (int u = 0; u < 2; u++) {
        int vid = u * 256 + t;
        int row = vid >> 2, kq = (vid & 3) * 8;
        const float* s = (const float*)Bv + (size_t)(j0 + row) * ldb + k0 + kq;
        float4 f0 = *(const float4*)s;
        float4 f1 = *(const float4*)(s + 4);
        union { unsigned short h[8]; int4 v; } pk;
        pk.h[0] = f2bf(f0.x); pk.h[1] = f2bf(f0.y);
        pk.h[2] = f2bf(f0.z); pk.h[3] = f2bf(f0.w);
        pk.h[4] = f2bf(f1.x); pk.h[5] = f2bf(f1.y);
        pk.h[6] = f2bf(f1.z); pk.h[7] = f2bf(f1.w);
        *(int4*)&Bs[(size_t)vid * 8] = pk.v;   // vid*8 shorts == row*32+kq
      }
    }
    __syncthreads();   // drains vmcnt (DMA) + lgkmcnt before LDS reads

    short8 af[4], bfr[4];
    #pragma unroll
    for (int tm = 0; tm < 4; tm++)
      af[tm] = *(const short8*)&As[(wm + tm * 16 + lr) * 32 + lq * 8];
    #pragma unroll
    for (int tn = 0; tn < 4; tn++)
      bfr[tn] = *(const short8*)&Bs[(wn + tn * 16 + lr) * 32 + lq * 8];

    #pragma unroll
    for (int tm = 0; tm < 4; tm++)
      #pragma unroll
      for (int tn = 0; tn < 4; tn++)
        acc[tm][tn] = __builtin_amdgcn_mfma_f32_16x16x32_bf16(
            af[tm], bfr[tn], acc[tm][tn], 0, 0, 0);
    __syncthreads();
  }

  if (CMODE == 2) {
    // C/D layout: col=lane&15, row=lq*4+reg.
    #pragma unroll
    for (int tn = 0; tn < 4; tn++) {
      float s = 0.f;
      #pragma unroll
      for (int tm = 0; tm < 4; tm++)
        #pragma unroll
        for (int r = 0; r < 4; r++) s += tanhf(acc[tm][tn][r]);
      s += __shfl_xor(s, 16);
      s += __shfl_xor(s, 32);
      if (lq == 0) atomicAdd(&colsum[j0 + wn + tn * 16 + lr], s);
    }
  } else {
    #pragma unroll
    for (int tm = 0; tm < 4; tm++)
      #pragma unroll
      for (int tn = 0; tn < 4; tn++)
        #pragma unroll
        for (int r = 0; r < 4; r++) {
          int row = i0 + wm + tm * 16 + lq * 4 + r;
          int col = j0 + wn + tn * 16 + lr;
          if (CMODE == 0)
            ((float*)Cv)[(size_t)row * ldc + col] = acc[tm][tn][r];
          else
            ((unsigned short*)Cv)[(size_t)row * ldc + col] = f2bf(acc[tm][tn][r]);
        }
  }
}

// Tt_bf[key][l] = bf16(T[l][key]); T [2048][4096] fp32.
__global__ __launch_bounds__(256) void transpose_bf16(
    const float* __restrict__ T, unsigned short* __restrict__ Tt)
{
  __shared__ float tile[64][65];
  const int tx = threadIdx.x & 63;
  const int ty = threadIdx.x >> 6;
  const int k0 = blockIdx.x * 64;
  const int l0 = blockIdx.y * 64;
  #pragma unroll
  for (int u = 0; u < 16; u++) {
    int row = ty * 16 + u;
    tile[row][tx] = T[(size_t)(l0 + row) * 4096 + k0 + tx];
  }
  __syncthreads();
  #pragma unroll
  for (int u = 0; u < 16; u++) {
    int row = ty * 16 + u;
    Tt[(size_t)(k0 + row) * 2048 + l0 + tx] = f2bf(tile[tx][row]);
  }
}

// out[i] = bf16(in[i]), 8 elements/thread, packed 16B stores.
__global__ __launch_bounds__(256) void cvt_bf16(
    const float* __restrict__ in, unsigned short* __restrict__ out, int n8)
{
  int i = blockIdx.x * 256 + threadIdx.x;
  if (i >= n8) return;
  float4 f0 = ((const float4*)in)[(size_t)i * 2];
  float4 f1 = ((const float4*)in)[(size_t)i * 2 + 1];
  union { unsigned short h[8]; int4 v; } pk;
  pk.h[0] = f2bf(f0.x); pk.h[1] = f2bf(f0.y);
  pk.h[2] = f2bf(f0.z); pk.h[3] = f2bf(f0.w);
  pk.h[4] = f2bf(f1.x); pk.h[5] = f2bf(f1.y);
  pk.h[6] = f2bf(f1.z); pk.h[7] = f2bf(f1.w);
  ((int4*)out)[i] = pk.v;
}

// Row softmax over 4096 fp32, writes bf16 IN PLACE at row start.
__global__ __launch_bounds__(256) void softmax_bf16(float* __restrict__ S)
{
  float* p = S + (size_t)blockIdx.x * 4096;
  const int tid = threadIdx.x;
  float4 v[4];
  #pragma unroll
  for (int u = 0; u < 4; u++) v[u] = ((const float4*)p)[tid * 4 + u];

  float m = -3.4e38f;
  #pragma unroll
  for (int u = 0; u < 4; u++)
    m = fmaxf(m, fmaxf(fmaxf(v[u].x, v[u].y), fmaxf(v[u].z, v[u].w)));
  #pragma unroll
  for (int off = 32; off > 0; off >>= 1) m = fmaxf(m, __shfl_down(m, off, 64));
  __shared__ float redm[4];
  if ((tid & 63) == 0) redm[tid >> 6] = m;
  __syncthreads();
  m = fmaxf(fmaxf(redm[0], redm[1]), fmaxf(redm[2], redm[3]));

  float s = 0.f;
  #pragma unroll
  for (int u = 0; u < 4; u++) {
    v[u].x = __expf(v[u].x - m); v[u].y = __expf(v[u].y - m);
    v[u].z = __expf(v[u].z - m); v[u].w = __expf(v[u].w - m);
    s += v[u].x + v[u].y + v[u].z + v[u].w;
  }
  #pragma unroll
  for (int off = 32; off > 0; off >>= 1) s += __shfl_down(s, off, 64);
  __shared__ float reds[4];
  if ((tid & 63) == 0) reds[tid >> 6] = s;
  __syncthreads();
  s = reds[0] + reds[1] + reds[2] + reds[3];
  const float inv = 1.f / s;

  unsigned short* a = (unsigned short*)p;
  #pragma unroll
  for (int h = 0; h < 2; h++) {
    union { unsigned short u[8]; int4 q; } pk;
    #pragma unroll
    for (int j = 0; j < 2; j++) {
      float4 w = v[h * 2 + j];
      pk.u[j * 4 + 0] = f2bf(w.x * inv); pk.u[j * 4 + 1] = f2bf(w.y * inv);
      pk.u[j * 4 + 2] = f2bf(w.z * inv); pk.u[j * 4 + 3] = f2bf(w.w * inv);
    }
    ((int4*)a)[tid * 2 + h] = pk.q;
  }
}

__global__ void zero_k(float* p, int n)
{
  int i = blockIdx.x * 256 + threadIdx.x;
  if (i < n) p[i] = 0.f;
}

// scores /= max; softmax; -> FP32 out (2048).
__global__ __launch_bounds__(256) void finalize_k(const float* __restrict__ scores,
                                                  float* __restrict__ out)
{
  const int tid = threadIdx.x;
  float s[8];
  #pragma unroll
  for (int u = 0; u < 8; u++) s[u] = scores[tid + u * 256];

  __shared__ float red[4];

  float m = -3.4e38f;
  #pragma unroll
  for (int u = 0; u < 8; u++) m = fmaxf(m, s[u]);
  #pragma unroll
  for (int off = 32; off > 0; off >>= 1) m = fmaxf(m, __shfl_down(m, off, 64));
  if ((tid & 63) == 0) red[tid >> 6] = m;
  __syncthreads();
  m = fmaxf(fmaxf(red[0], red[1]), fmaxf(red[2], red[3]));
  __syncthreads();

  const float inv1 = 1.f / m;
  #pragma unroll
  for (int u = 0; u < 8; u++) s[u] *= inv1;

  float m2 = -3.4e38f;
  #pragma unroll
  for (int u = 0; u < 8; u++) m2 = fmaxf(m2, s[u]);
  #pragma unroll
  for (int off = 32; off > 0; off >>= 1) m2 = fmaxf(m2, __shfl_down(m2, off, 64));
  if ((tid & 63) == 0) red[tid >> 6] = m2;
  __syncthreads();
  m2 = fmaxf(fmaxf(red[0], red[1]), fmaxf(red[2], red[3]));
  __syncthreads();

  float sum = 0.f;
  #pragma unroll
  for (int u = 0; u < 8; u++) { s[u] = expf(s[u] - m2); sum += s[u]; }
  #pragma unroll
  for (int off = 32; off > 0; off >>= 1) sum += __shfl_down(sum, off, 64);
  if ((tid & 63) == 0) red[tid >> 6] = sum;
  __syncthreads();
  sum = red[0] + red[1] + red[2] + red[3];

  const float invs = 1.f / sum;
  #pragma unroll
  for (int u = 0; u < 8; u++)
    out[tid + u * 256] = s[u] * invs;
}

extern "C" void kernel_launch(void* const* d_in, const int* in_sizes, int n_in,
                              void* d_out, int out_size, void* d_ws, size_t ws_size,
                              hipStream_t stream)
{
  const float* T    = (const float*)d_in[0];   // [2048][4096]
  const float* Win  = (const float*)d_in[1];   // [2048][2048] 'ml'
  const float* Wout = (const float*)d_in[2];   // [2048][4096] 'lc'
  float* out = (float*)d_out;

  // tier1 fixed: Tt(16.78M) Tb(16.78M) Winb(8.39M) Woutb(16.78M) comb(33.55M)
  const size_t FIX1 = 92274688ull + 16384;
  int R = 1024; bool pre = false;
  if      (ws_size >= FIX1 + (size_t)4096 * 16384) { pre = true; R = 4096; }
  else if (ws_size >= FIX1 + (size_t)2048 * 16384) { pre = true; R = 2048; }
  else if (ws_size >= FIX1 + (size_t)1024 * 16384) { pre = true; R = 1024; }

  unsigned short* Tt = (unsigned short*)d_ws;

  if (pre) {
    unsigned short* Tb    = Tt + (size_t)4096 * 2048;
    unsigned short* Winb  = Tb + (size_t)2048 * 4096;
    unsigned short* Woutb = Winb + (size_t)2048 * 2048;
    unsigned short* comb  = Woutb + (size_t)2048 * 4096;
    float* S      = (float*)(comb + (size_t)4096 * 4096);
    float* scores = S + (size_t)R * 4096;

    zero_k<<<8, 256, 0, stream>>>(scores, 2048);
    transpose_bf16<<<dim3(64, 32), 256, 0, stream>>>(T, Tt);
    cvt_bf16<<<4096, 256, 0, stream>>>(T, Tb, 1048576);
    cvt_bf16<<<2048, 256, 0, stream>>>(Win, Winb, 524288);
    cvt_bf16<<<4096, 256, 0, stream>>>(Wout, Woutb, 1048576);

    // GEMM1: Q -> comb[:,2048:]
    mfma_gemm<0, 1><<<dim3(16, 32), 256, 0, stream>>>(
        Tt, Winb, comb + 2048, nullptr, 2048, 2048, 2048, 4096);
    for (int c = 0; c < 4096 / R; c++) {
      const size_t d0 = (size_t)c * R;
      mfma_gemm<0, 0><<<dim3(32, R / 128), 256, 0, stream>>>(
          comb + d0 * 4096 + 2048, Tt, S, nullptr, 2048, 4096, 2048, 4096);
      softmax_bf16<<<R, 256, 0, stream>>>(S);
      mfma_gemm<0, 1><<<dim3(16, R / 128), 256, 0, stream>>>(
          (unsigned short*)S, Tb, comb + d0 * 4096, nullptr, 4096, 8192, 4096, 4096);
    }
    mfma_gemm<0, 2><<<dim3(16, 32), 256, 0, stream>>>(
        comb, Woutb, nullptr, scores, 4096, 4096, 4096, 4096);
    finalize_k<<<1, 256, 0, stream>>>(scores, out);
  } else {
    // tier0: r12 layout (67,117,056 B proven to fit), inline cvt for fp32 B.
    unsigned short* comb = Tt + (size_t)4096 * 2048;
    float* S      = (float*)(comb + (size_t)4096 * 4096);
    float* scores = S + (size_t)1024 * 4096;

    zero_k<<<8, 256, 0, stream>>>(scores, 2048);
    transpose_bf16<<<dim3(64, 32), 256, 0, stream>>>(T, Tt);

    mfma_gemm<1, 1><<<dim3(16, 32), 256, 0, stream>>>(
        Tt, Win, comb + 2048, nullptr, 2048, 2048, 2048, 4096);
    for (int c = 0; c < 4; c++) {
      const size_t d0 = (size_t)c * 1024;
      mfma_gemm<0, 0><<<dim3(32, 8), 256, 0, stream>>>(
          comb + d0 * 4096 + 2048, Tt, S, nullptr, 2048, 4096, 2048, 4096);
      softmax_bf16<<<1024, 256, 0, stream>>>(S);
      mfma_gemm<1, 1><<<dim3(16, 8), 256, 0, stream>>>(
          (unsigned short*)S, T, comb + d0 * 4096, nullptr, 4096, 8192, 4096, 4096);
    }
    mfma_gemm<1, 2><<<dim3(16, 32), 256, 0, stream>>>(
        comb, Wout, nullptr, scores, 4096, 4096, 4096, 4096);
    finalize_k<<<1, 256, 0, stream>>>(scores, out);
  }
}